// Round 2
// baseline (1543.098 us; speedup 1.0000x reference)
//
#include <hip/hip_runtime.h>
#include <cstdint>
#include <cmath>

#define DD 2048
#define TT 2048
#define HH 16
#define HDD 128
#define MROWS 4096  // B*T

typedef __attribute__((ext_vector_type(8))) short s16x8;
typedef __attribute__((ext_vector_type(4))) float f32x4;

typedef const __attribute__((address_space(1))) void gvoid;
typedef __attribute__((address_space(3))) void lvoid;

__device__ __forceinline__ void async_cp16(const void* g, void* l) {
    __builtin_amdgcn_global_load_lds((gvoid*)g, (lvoid*)l, 16, 0, 0);
}

__device__ __forceinline__ unsigned short f2bf(float f) {
    unsigned int u = __float_as_uint(f);
    u += 0x7fffu + ((u >> 16) & 1u);
    return (unsigned short)(u >> 16);
}

__device__ __forceinline__ void store4bf(unsigned short* p, float a, float b, float c, float d) {
    union { unsigned short u[4]; uint2 v; } x;
    x.u[0] = f2bf(a); x.u[1] = f2bf(b); x.u[2] = f2bf(c); x.u[3] = f2bf(d);
    *(uint2*)p = x.v;
}

// ---------------- fp32 -> bf16 convert with 16-row lin/gate interleave ----------------
__global__ __launch_bounds__(256) void cvt_ilv(const float* __restrict__ W,
                                               const float* __restrict__ Wg,
                                               unsigned short* __restrict__ out, int k4shift) {
    int g = blockIdx.x * 256 + threadIdx.x;
    int rp = g >> k4shift;
    int c4 = g & ((1 << k4shift) - 1);
    int jb = rp >> 5, s = rp & 15, sel = (rp >> 4) & 1;
    const float* src = (sel ? Wg : W) + (((size_t)(jb * 16 + s)) << (k4shift + 2)) + c4 * 4;
    float4 v = *(const float4*)src;
    store4bf(out + (((size_t)rp) << (k4shift + 2)) + c4 * 4, v.x, v.y, v.z, v.w);
}

// ---------------- LayerNorm (fp32 in, bf16 out) ----------------
__global__ __launch_bounds__(256) void ln_bf16(const float* __restrict__ x,
                                               const float* __restrict__ gg,
                                               const float* __restrict__ bb,
                                               unsigned short* __restrict__ out) {
    __shared__ float red[8];
    const int row = blockIdx.x, t = threadIdx.x;
    const float* xr = x + (size_t)row * DD;
    float4 a = ((const float4*)xr)[t];
    float4 c = ((const float4*)xr)[t + 256];
    float s = a.x + a.y + a.z + a.w + c.x + c.y + c.z + c.w;
    float q = a.x*a.x + a.y*a.y + a.z*a.z + a.w*a.w + c.x*c.x + c.y*c.y + c.z*c.z + c.w*c.w;
    #pragma unroll
    for (int m = 1; m < 64; m <<= 1) { s += __shfl_xor(s, m); q += __shfl_xor(q, m); }
    if ((t & 63) == 0) { red[t >> 6] = s; red[4 + (t >> 6)] = q; }
    __syncthreads();
    s = red[0] + red[1] + red[2] + red[3];
    q = red[4] + red[5] + red[6] + red[7];
    float mean = s * (1.f / DD);
    float var = q * (1.f / DD) - mean * mean;
    float rstd = rsqrtf(var + 1e-5f);
    float4 g1 = ((const float4*)gg)[t], b1 = ((const float4*)bb)[t];
    float4 g2 = ((const float4*)gg)[t + 256], b2 = ((const float4*)bb)[t + 256];
    unsigned short* orow = out + (size_t)row * DD;
    store4bf(orow + 4 * t,
             (a.x - mean) * rstd * g1.x + b1.x, (a.y - mean) * rstd * g1.y + b1.y,
             (a.z - mean) * rstd * g1.z + b1.z, (a.w - mean) * rstd * g1.w + b1.w);
    store4bf(orow + 1024 + 4 * t,
             (c.x - mean) * rstd * g2.x + b2.x, (c.y - mean) * rstd * g2.y + b2.y,
             (c.z - mean) * rstd * g2.z + b2.z, (c.w - mean) * rstd * g2.w + b2.w);
}

// ---------------- gated GEMM, 256x256 8-phase schedule (deep prefetch) ----------------
// out[m,n] = epi( (A.Wi^T)[m, 2n..] paired lin/gate ), Wi = 16-row interleaved (W,Wg).
// BM=256, BN'=256, BK=64; 512 thr = 8 waves (2m x 4n); per-wave 128m x 64n'.
// LDS 128KB: A slots [0,64K), B slots [64K,128K); slot = [kh][p(0..127)][64 cols],
// paired rows: lr=2p+(chunk>>2), k = kh*32 + (chunk&3)*8; chunk ^= (p&7) (conflict-free).
// Phases per K-tile: P1(iq0,kh0) P2(iq1,kh0) P3(iq0,kh1) P4(iq1,kh1).
// Staging (next tile): A0+B0 issued P1, A1+B1 issued P2 (after VM4).
// Waits: VM4@P2 drains prev A1B1 (distance 4 phases); VM4@P4 drains next-tile A0B0
// (distance 3 phases). Never vmcnt(0) in main loop. Each pre-MMA barrier is followed
// by lgkmcnt(0)+sched_barrier(0) to lockstep the MFMA cluster (rule #18).
#define G8_LDA(base, iq) do { \
    _Pragma("unroll") \
    for (int i2_ = 0; i2_ < 4; i2_++) \
        af[i2_] = *(const s16x8*)(lds + (base) + aRd + ((iq) * 4 + i2_) * 1024); \
} while (0)
#define G8_LDB(base) do { \
    _Pragma("unroll") \
    for (int j_ = 0; j_ < 4; j_++) \
        bf[j_] = *(const s16x8*)(lds + (base) + bRd + j_ * 1024); \
} while (0)
#define G8_MMA(iq) do { \
    __builtin_amdgcn_s_setprio(1); \
    _Pragma("unroll") \
    for (int i2_ = 0; i2_ < 4; i2_++) { \
        _Pragma("unroll") \
        for (int j_ = 0; j_ < 4; j_++) \
            acc[(iq) * 4 + i2_][j_] = __builtin_amdgcn_mfma_f32_16x16x32_bf16( \
                af[i2_], bf[j_], acc[(iq) * 4 + i2_][j_], 0, 0, 0); \
    } \
    __builtin_amdgcn_s_setprio(0); \
} while (0)
#define G8_BAR() __builtin_amdgcn_s_barrier()
#define G8_SCB() __builtin_amdgcn_sched_barrier(0)
#define G8_LGK0() asm volatile("s_waitcnt lgkmcnt(0)" ::: "memory")
#define G8_VM4() asm volatile("s_waitcnt vmcnt(4)" ::: "memory")
#define G8_VM0() asm volatile("s_waitcnt vmcnt(0)" ::: "memory")
#define G8_CLUSTER(iq) do { G8_BAR(); G8_LGK0(); G8_SCB(); G8_MMA(iq); G8_BAR(); } while (0)

template <int EPI>
__global__ __launch_bounds__(512, 2) void gemm_gated8(
        const unsigned short* __restrict__ A, const unsigned short* __restrict__ Wi,
        const float* __restrict__ bias, const float* __restrict__ biasg,
        const float* __restrict__ resid, void* __restrict__ outp,
        int M, int Ntrue, int K) {
    __shared__ unsigned short lds_[65536];  // 128 KiB
    char* lds = (char*)lds_;
    const int t = threadIdx.x, lane = t & 63, wv = t >> 6;
    const int fr = lane & 15, fg = lane >> 4;
    const int wr = wv >> 2, wc = wv & 3;

    const int nM = M >> 8;
    const int nwg = gridDim.x;
    const int pid = blockIdx.x;
    const int swz = (pid & 7) * (nwg >> 3) + (pid >> 3);  // bijective: nwg%8==0 always here
    const int nt = swz / nM;
    const int mt = swz - nt * nM;
    const int m0 = mt << 8;
    const int np0 = nt << 8;

    // staging source pointers, inverse-swizzled so linear LDS dest holds swizzled layout
    const unsigned short* aP[2];
    const unsigned short* bP[2];
    int ldst[2];
    #pragma unroll
    for (int l = 0; l < 2; l++) {
        int idx = l * 512 + t;
        int p = idx >> 3, pc = idx & 7;
        int spc = pc ^ (p & 7);
        int lr = 2 * p + (spc >> 2);
        int ke = (spc & 3) * 8;
        aP[l] = A + (size_t)(m0 + lr) * K + ke;
        bP[l] = Wi + (size_t)(np0 + lr) * K + ke;
        ldst[l] = idx * 16;
    }
    // fragment read base offsets (conflict-free)
    const int chR = (((fr & 1) << 2) | fg) ^ ((fr >> 1) & 7);
    const int aRd = (wr * 64 + (fr >> 1)) * 128 + chR * 16;
    const int bRd = (wc * 32 + (fr >> 1)) * 128 + chR * 16;

    f32x4 acc[8][4];
    f32x4 zero4 = {0.f, 0.f, 0.f, 0.f};
    #pragma unroll
    for (int i = 0; i < 8; i++)
        #pragma unroll
        for (int j = 0; j < 4; j++) acc[i][j] = zero4;
    s16x8 af[4], bf[4];

    // prologue: stage full T0 (A0,B0 first, then A1,B1), wait only for kh0
    async_cp16(aP[0], lds + ldst[0]);
    async_cp16(aP[1], lds + ldst[1]);
    async_cp16(bP[0], lds + 65536 + ldst[0]);
    async_cp16(bP[1], lds + 65536 + ldst[1]);
    async_cp16(aP[0] + 32, lds + 16384 + ldst[0]);
    async_cp16(aP[1] + 32, lds + 16384 + ldst[1]);
    async_cp16(bP[0] + 32, lds + 65536 + 16384 + ldst[0]);
    async_cp16(bP[1] + 32, lds + 65536 + 16384 + ldst[1]);
    G8_VM4(); G8_BAR(); G8_SCB();

    const int NT = K >> 6;
    for (int kt = 0; kt < NT - 1; kt++) {
        const int sA = (kt & 1) << 15;
        const int sB = 65536 + sA;
        const int nAb = sA ^ 32768;
        const int nBb = 65536 + nAb;
        const int kn = (kt + 1) << 6;
        // P1 (iq0,kh0): stage next A0+B0
        G8_LDA(sA, 0); G8_LDB(sB);
        async_cp16(aP[0] + kn, lds + nAb + ldst[0]);
        async_cp16(aP[1] + kn, lds + nAb + ldst[1]);
        async_cp16(bP[0] + kn, lds + nBb + ldst[0]);
        async_cp16(bP[1] + kn, lds + nBb + ldst[1]);
        G8_CLUSTER(0);
        // P2 (iq1,kh0): drain prev A1B1 (enables P3), then stage next A1+B1
        G8_LDA(sA, 1);
        G8_VM4();
        async_cp16(aP[0] + kn + 32, lds + nAb + 16384 + ldst[0]);
        async_cp16(aP[1] + kn + 32, lds + nAb + 16384 + ldst[1]);
        async_cp16(bP[0] + kn + 32, lds + nBb + 16384 + ldst[0]);
        async_cp16(bP[1] + kn + 32, lds + nBb + 16384 + ldst[1]);
        G8_CLUSTER(1);
        // P3 (iq0,kh1)
        G8_LDA(sA + 16384, 0); G8_LDB(sB + 16384);
        G8_CLUSTER(0);
        // P4 (iq1,kh1): drain next-tile A0B0 (enables next P1)
        G8_LDA(sA + 16384, 1);
        G8_VM4();
        G8_CLUSTER(1);
    }
    {   // final tile: no staging; only leftover in flight is this tile's A1B1
        const int sA = ((NT - 1) & 1) << 15;
        const int sB = 65536 + sA;
        G8_LDA(sA, 0); G8_LDB(sB);
        G8_CLUSTER(0);
        G8_LDA(sA, 1);
        G8_VM0();
        G8_CLUSTER(1);
        G8_LDA(sA + 16384, 0); G8_LDB(sB + 16384);
        G8_CLUSTER(0);
        G8_LDA(sA + 16384, 1);
        G8_LGK0(); G8_SCB();
        G8_MMA(1);
    }

    // epilogue: pair acc[i][2jp] (lin) with acc[i][2jp+1] (gate)
    const int mB = m0 + wr * 128 + fg * 4;
    const int nB = (nt << 7) + wc * 32 + fr;  // true n
    if constexpr (EPI == 1) {
        // transposed V store: vT[(b*2048 + n)*2048 + tseq]
        const int b_ = m0 >> 11;
        unsigned short* vt = (unsigned short*)outp;
        #pragma unroll
        for (int i = 0; i < 8; i++)
            #pragma unroll
            for (int jp = 0; jp < 2; jp++) {
                const int n = nB + jp * 16;
                const float bn = bias[n], bgn = biasg[n];
                float g4[4];
                #pragma unroll
                for (int r = 0; r < 4; r++) {
                    float lin = acc[i][2 * jp][r] + bn;
                    float gt = acc[i][2 * jp + 1][r] + bgn;
                    g4[r] = lin / (1.f + __expf(-gt));
                }
                unsigned short* dst = vt + ((size_t)b_ * 2048 + n) * 2048 +
                                      (m0 & 2047) + wr * 128 + i * 16 + fg * 4;
                store4bf(dst, g4[0], g4[1], g4[2], g4[3]);
            }
    } else {
        #pragma unroll
        for (int i = 0; i < 8; i++)
            #pragma unroll
            for (int jp = 0; jp < 2; jp++) {
                const int n = nB + jp * 16;
                const float bn = bias[n], bgn = biasg[n];
                #pragma unroll
                for (int r = 0; r < 4; r++) {
                    const int m = mB + i * 16 + r;
                    float lin = acc[i][2 * jp][r] + bn;
                    float gt = acc[i][2 * jp + 1][r] + bgn;
                    float gv = lin / (1.f + __expf(-gt));
                    if constexpr (EPI == 0) {
                        ((unsigned short*)outp)[(size_t)m * Ntrue + n] = f2bf(gv);
                    } else if constexpr (EPI == 2) {
                        ((float*)outp)[(size_t)m * Ntrue + n] =
                            resid[(size_t)m * Ntrue + n] + gv;
                    } else {
                        float ge = 0.5f * gv * (1.f + erff(gv * 0.70710678118f));
                        ((unsigned short*)outp)[(size_t)m * Ntrue + n] = f2bf(ge);
                    }
                }
            }
    }
}

// ---------------- flash attention v2 (unchanged this round) ----------------
__global__ __launch_bounds__(256, 4) void attn_flash2(const unsigned short* __restrict__ Q,
                                                      const unsigned short* __restrict__ Kb,
                                                      const unsigned short* __restrict__ VT,
                                                      unsigned short* __restrict__ Y) {
    __shared__ unsigned short sK[64 * 128];
    __shared__ unsigned short sV[128 * 64];
    __shared__ unsigned short sP[4 * 1024];
    const int t = threadIdx.x, lane = t & 63, wv = t >> 6;
    const int bx = blockIdx.x;
    const int qblk = bx & 31;
    const int h = (bx >> 5) & 15;
    const int b = bx >> 9;
    const int q0 = qblk * 64 + wv * 16;
    const int fr = lane & 15, fg = lane >> 4;

    s16x8 qf[4];
    const unsigned short* qbase = Q + ((size_t)(b * TT + q0 + fr)) * DD + h * HDD + fg * 8;
    #pragma unroll
    for (int s = 0; s < 4; s++) qf[s] = *(const s16x8*)(qbase + s * 32);

    const unsigned short* kSrc[4];
    const unsigned short* vSrc[4];
    #pragma unroll
    for (int r = 0; r < 4; r++) {
        int R = r * 16 + (t >> 4);
        int c = (t & 15) ^ ((t >> 4) & 15);
        kSrc[r] = Kb + (size_t)(b * TT + R) * DD + h * HDD + c * 8;
        int hd = r * 32 + (t >> 3);
        int cv = (t & 7) ^ ((t >> 3) & 7);
        vSrc[r] = VT + ((size_t)((b * HH + h) * HDD + hd)) * TT + cv * 8;
    }
    unsigned short* sPw = sP + wv * 1024;

    f32x4 zero4 = {0.f, 0.f, 0.f, 0.f};
    f32x4 o[8];
    #pragma unroll
    for (int jo = 0; jo < 8; jo++) o[jo] = zero4;
    float Mx[4], L[4];
    #pragma unroll
    for (int r = 0; r < 4; r++) { Mx[r] = -1e30f; L[r] = 0.f; }
    const float scale = 0.08838834764831845f;

    for (int tk0 = 0; tk0 < TT; tk0 += 64) {
        #pragma unroll
        for (int r = 0; r < 4; r++) {
            async_cp16(kSrc[r] + (size_t)tk0 * DD, sK + r * 2048 + t * 8);
            async_cp16(vSrc[r] + tk0, sV + r * 2048 + t * 8);
        }
        __syncthreads();

        f32x4 sac[4];
        #pragma unroll
        for (int j = 0; j < 4; j++) sac[j] = zero4;
        #pragma unroll
        for (int j = 0; j < 4; j++)
            #pragma unroll
            for (int s = 0; s < 4; s++) {
                s16x8 kf = *(const s16x8*)(sK + (j * 16 + fr) * 128 + (((s * 4 + fg) ^ fr) * 8));
                sac[j] = __builtin_amdgcn_mfma_f32_16x16x32_bf16(qf[s], kf, sac[j], 0, 0, 0);
            }

        float alpha[4];
        #pragma unroll
        for (int j = 0; j < 4; j++)
            #pragma unroll
            for (int r = 0; r < 4; r++) sac[j][r] *= scale;
        #pragma unroll
        for (int r = 0; r < 4; r++) {
            float mx = fmaxf(fmaxf(sac[0][r], sac[1][r]), fmaxf(sac[2][r], sac[3][r]));
            mx = fmaxf(mx, __shfl_xor(mx, 1));
            mx = fmaxf(mx, __shfl_xor(mx, 2));
            mx = fmaxf(mx, __shfl_xor(mx, 4));
            mx = fmaxf(mx, __shfl_xor(mx, 8));
            float mnew = fmaxf(Mx[r], mx);
            alpha[r] = __expf(Mx[r] - mnew);
            Mx[r] = mnew;
        }
        float rs[4] = {0.f, 0.f, 0.f, 0.f};
        #pragma unroll
        for (int j = 0; j < 4; j++)
            #pragma unroll
            for (int r = 0; r < 4; r++) {
                float p = __expf(sac[j][r] - Mx[r]);
                rs[r] += p;
                int qr = fg * 4 + r;
                int cc = (j * 2 + (fr >> 3)) ^ (qr & 7);
                sPw[qr * 64 + cc * 8 + (fr & 7)] = f2bf(p);
            }
        #pragma unroll
        for (int r = 0; r < 4; r++) {
            float tsum = rs[r];
            tsum += __shfl_xor(tsum, 1);
            tsum += __shfl_xor(tsum, 2);
            tsum += __shfl_xor(tsum, 4);
            tsum += __shfl_xor(tsum, 8);
            L[r] = L[r] * alpha[r] + tsum;
        }
        #pragma unroll
        for (int jo = 0; jo < 8; jo++)
            #pragma unroll
            for (int r = 0; r < 4; r++) o[jo][r] *= alpha[r];

        s16x8 pa[2];
        #pragma unroll
        for (int ks = 0; ks < 2; ks++)
            pa[ks] = *(const s16x8*)(sPw + fr * 64 + (((ks * 4 + fg) ^ (fr & 7)) * 8));
        #pragma unroll
        for (int jo = 0; jo < 8; jo++)
            #pragma unroll
            for (int ks = 0; ks < 2; ks++) {
                s16x8 vf = *(const s16x8*)(sV + (jo * 16 + fr) * 64 + (((ks * 4 + fg) ^ (fr & 7)) * 8));
                o[jo] = __builtin_amdgcn_mfma_f32_16x16x32_bf16(pa[ks], vf, o[jo], 0, 0, 0);
            }
        __syncthreads();
    }
    float Linv[4];
    #pragma unroll
    for (int r = 0; r < 4; r++) Linv[r] = 1.f / L[r];
    #pragma unroll
    for (int jo = 0; jo < 8; jo++)
        #pragma unroll
        for (int r = 0; r < 4; r++) {
            float val = o[jo][r] * Linv[r];
            Y[((size_t)(b * TT + q0 + fg * 4 + r)) * DD + h * HDD + jo * 16 + fr] = f2bf(val);
        }
}

// ---------------- launch ----------------
extern "C" void kernel_launch(void* const* d_in, const int* in_sizes, int n_in,
                              void* d_out, int out_size, void* d_ws, size_t ws_size,
                              hipStream_t stream) {
    const float* x = (const float*)d_in[0];
    auto F = [&](int i) { return (const float*)d_in[i]; };
    char* ws = (char*)d_ws;
    const size_t MB = 1ull << 20;

    unsigned short* wi_q  = (unsigned short*)(ws + 0 * MB);
    unsigned short* wi_k  = (unsigned short*)(ws + 16 * MB);
    unsigned short* wi_v  = (unsigned short*)(ws + 32 * MB);
    unsigned short* wi_o  = (unsigned short*)(ws + 48 * MB);
    unsigned short* wi_in = (unsigned short*)(ws + 64 * MB);
    unsigned short* wi_ot = (unsigned short*)(ws + 128 * MB);
    cvt_ilv<<<dim3(8192), dim3(256), 0, stream>>>(F(1), F(3), wi_q, 9);
    cvt_ilv<<<dim3(8192), dim3(256), 0, stream>>>(F(5), F(7), wi_k, 9);
    cvt_ilv<<<dim3(8192), dim3(256), 0, stream>>>(F(9), F(11), wi_v, 9);
    cvt_ilv<<<dim3(8192), dim3(256), 0, stream>>>(F(13), F(15), wi_o, 9);
    cvt_ilv<<<dim3(32768), dim3(256), 0, stream>>>(F(17), F(19), wi_in, 9);
    cvt_ilv<<<dim3(32768), dim3(256), 0, stream>>>(F(21), F(23), wi_ot, 11);

    unsigned short* hbf = (unsigned short*)(ws + 192 * MB);
    unsigned short* qb  = (unsigned short*)(ws + 208 * MB);
    unsigned short* kb  = (unsigned short*)(ws + 224 * MB);
    unsigned short* vtb = (unsigned short*)(ws + 240 * MB);
    unsigned short* yb  = (unsigned short*)(ws + 256 * MB);
    unsigned short* ub  = (unsigned short*)(ws + 208 * MB);  // overlaps q/k/vT/y (dead by then)
    float* x1 = (float*)(ws + 272 * MB);

    ln_bf16<<<dim3(MROWS), dim3(256), 0, stream>>>(x, F(25), F(26), hbf);

    dim3 blk(512);
    gemm_gated8<0><<<dim3(256), blk, 0, stream>>>(hbf, wi_q, F(2), F(4), nullptr, qb, MROWS, DD, DD);
    gemm_gated8<0><<<dim3(256), blk, 0, stream>>>(hbf, wi_k, F(6), F(8), nullptr, kb, MROWS, DD, DD);
    gemm_gated8<1><<<dim3(256), blk, 0, stream>>>(hbf, wi_v, F(10), F(12), nullptr, vtb, MROWS, DD, DD);

    attn_flash2<<<dim3(1024), dim3(256), 0, stream>>>(qb, kb, vtb, yb);

    gemm_gated8<2><<<dim3(256), blk, 0, stream>>>(yb, wi_o, F(14), F(16), x, x1, MROWS, DD, DD);

    ln_bf16<<<dim3(MROWS), dim3(256), 0, stream>>>(x1, F(27), F(28), hbf);

    gemm_gated8<3><<<dim3(1024), blk, 0, stream>>>(hbf, wi_in, F(18), F(20), nullptr, ub, MROWS, 4 * DD, DD);
    gemm_gated8<2><<<dim3(256), blk, 0, stream>>>(ub, wi_ot, F(22), F(24), x1, (float*)d_out, MROWS, DD, 4 * DD);
}

// Round 3
// 1370.270 us; speedup vs baseline: 1.1261x; 1.1261x over previous
//
#include <hip/hip_runtime.h>
#include <cstdint>
#include <cmath>

#define DD 2048
#define TT 2048
#define HH 16
#define HDD 128
#define MROWS 4096  // B*T

typedef __attribute__((ext_vector_type(8))) short s16x8;
typedef __attribute__((ext_vector_type(4))) float f32x4;

typedef const __attribute__((address_space(1))) void gvoid;
typedef __attribute__((address_space(3))) void lvoid;

__device__ __forceinline__ void async_cp16(const void* g, void* l) {
    __builtin_amdgcn_global_load_lds((gvoid*)g, (lvoid*)l, 16, 0, 0);
}

__device__ __forceinline__ unsigned short f2bf(float f) {
    unsigned int u = __float_as_uint(f);
    u += 0x7fffu + ((u >> 16) & 1u);
    return (unsigned short)(u >> 16);
}

__device__ __forceinline__ void store4bf(unsigned short* p, float a, float b, float c, float d) {
    union { unsigned short u[4]; uint2 v; } x;
    x.u[0] = f2bf(a); x.u[1] = f2bf(b); x.u[2] = f2bf(c); x.u[3] = f2bf(d);
    *(uint2*)p = x.v;
}

// ---------------- fp32 -> bf16 convert with 16-row lin/gate interleave ----------------
__global__ __launch_bounds__(256) void cvt_ilv(const float* __restrict__ W,
                                               const float* __restrict__ Wg,
                                               unsigned short* __restrict__ out, int k4shift) {
    int g = blockIdx.x * 256 + threadIdx.x;
    int rp = g >> k4shift;
    int c4 = g & ((1 << k4shift) - 1);
    int jb = rp >> 5, s = rp & 15, sel = (rp >> 4) & 1;
    const float* src = (sel ? Wg : W) + (((size_t)(jb * 16 + s)) << (k4shift + 2)) + c4 * 4;
    float4 v = *(const float4*)src;
    store4bf(out + (((size_t)rp) << (k4shift + 2)) + c4 * 4, v.x, v.y, v.z, v.w);
}

// ---------------- LayerNorm (fp32 in, bf16 out) ----------------
__global__ __launch_bounds__(256) void ln_bf16(const float* __restrict__ x,
                                               const float* __restrict__ gg,
                                               const float* __restrict__ bb,
                                               unsigned short* __restrict__ out) {
    __shared__ float red[8];
    const int row = blockIdx.x, t = threadIdx.x;
    const float* xr = x + (size_t)row * DD;
    float4 a = ((const float4*)xr)[t];
    float4 c = ((const float4*)xr)[t + 256];
    float s = a.x + a.y + a.z + a.w + c.x + c.y + c.z + c.w;
    float q = a.x*a.x + a.y*a.y + a.z*a.z + a.w*a.w + c.x*c.x + c.y*c.y + c.z*c.z + c.w*c.w;
    #pragma unroll
    for (int m = 1; m < 64; m <<= 1) { s += __shfl_xor(s, m); q += __shfl_xor(q, m); }
    if ((t & 63) == 0) { red[t >> 6] = s; red[4 + (t >> 6)] = q; }
    __syncthreads();
    s = red[0] + red[1] + red[2] + red[3];
    q = red[4] + red[5] + red[6] + red[7];
    float mean = s * (1.f / DD);
    float var = q * (1.f / DD) - mean * mean;
    float rstd = rsqrtf(var + 1e-5f);
    float4 g1 = ((const float4*)gg)[t], b1 = ((const float4*)bb)[t];
    float4 g2 = ((const float4*)gg)[t + 256], b2 = ((const float4*)bb)[t + 256];
    unsigned short* orow = out + (size_t)row * DD;
    store4bf(orow + 4 * t,
             (a.x - mean) * rstd * g1.x + b1.x, (a.y - mean) * rstd * g1.y + b1.y,
             (a.z - mean) * rstd * g1.z + b1.z, (a.w - mean) * rstd * g1.w + b1.w);
    store4bf(orow + 1024 + 4 * t,
             (c.x - mean) * rstd * g2.x + b2.x, (c.y - mean) * rstd * g2.y + b2.y,
             (c.z - mean) * rstd * g2.z + b2.z, (c.w - mean) * rstd * g2.w + b2.w);
}

// ---------------- gated GEMM, 256x256, 4 phases / K-tile, 2 barriers / K-tile ----------
// out[m,n] = epi( (A.Wi^T)[m, 2n..] paired lin/gate ), Wi = 16-row interleaved (W,Wg).
// BM=256, BN'=256, BK=64; 512 thr = 8 waves (2m x 4n); per-wave 128m x 64n'.
// LDS 128KB double-buffered: A slots [0,64K), B slots [64K,128K);
// slot = [kh][p(0..127)][64 cols], lr=2p+(chunk>>2), k=kh*32+(chunk&3)*8, chunk^=(p&7).
// Phases: P1(iq0,kh0)+stage nA0; P2(iq1,kh0)+stage nB0, MMA then VM4+BAR;
//         P3(iq0,kh1)+stage nA1; P4(iq1,kh1)+stage nB1, MMA then VM4+BAR.
// Only 2 barriers/K-tile (both after a VM4 drain). Hazard proof:
//  - stage into nAb/nBb: those buffers were last READ in the previous tile (P4/P3);
//    the previous tile's trailing BAR orders all reads before this tile's stages.
//  - reads of staged data: kh1 reads (P3) follow VM4@P2+BAR (drains prev A1B1);
//    next-tile kh0 reads follow VM4@P4+BAR (drains this tile's nA0/nB0).
// vmcnt never 0 in main loop; compiler emits fine-grained lgkmcnt for ds_read->MFMA.
#define G8_LDA(base, iq) do { \
    _Pragma("unroll") \
    for (int i2_ = 0; i2_ < 4; i2_++) \
        af[i2_] = *(const s16x8*)(lds + (base) + aRd + ((iq) * 4 + i2_) * 1024); \
} while (0)
#define G8_LDB(base) do { \
    _Pragma("unroll") \
    for (int j_ = 0; j_ < 4; j_++) \
        bf[j_] = *(const s16x8*)(lds + (base) + bRd + j_ * 1024); \
} while (0)
#define G8_MMA(iq) do { \
    __builtin_amdgcn_s_setprio(1); \
    _Pragma("unroll") \
    for (int i2_ = 0; i2_ < 4; i2_++) { \
        _Pragma("unroll") \
        for (int j_ = 0; j_ < 4; j_++) \
            acc[(iq) * 4 + i2_][j_] = __builtin_amdgcn_mfma_f32_16x16x32_bf16( \
                af[i2_], bf[j_], acc[(iq) * 4 + i2_][j_], 0, 0, 0); \
    } \
    __builtin_amdgcn_s_setprio(0); \
} while (0)
#define G8_BAR() __builtin_amdgcn_s_barrier()
#define G8_SCB() __builtin_amdgcn_sched_barrier(0)
#define G8_VM4() asm volatile("s_waitcnt vmcnt(4)" ::: "memory")
#define G8_VM0() asm volatile("s_waitcnt vmcnt(0)" ::: "memory")

template <int EPI>
__global__ __launch_bounds__(512, 2) void gemm_gated8(
        const unsigned short* __restrict__ A, const unsigned short* __restrict__ Wi,
        const float* __restrict__ bias, const float* __restrict__ biasg,
        const float* __restrict__ resid, void* __restrict__ outp,
        int M, int Ntrue, int K) {
    __shared__ unsigned short lds_[65536];  // 128 KiB
    char* lds = (char*)lds_;
    const int t = threadIdx.x, lane = t & 63, wv = t >> 6;
    const int fr = lane & 15, fg = lane >> 4;
    const int wr = wv >> 2, wc = wv & 3;

    const int nM = M >> 8;
    const int nwg = gridDim.x;
    const int pid = blockIdx.x;
    const int swz = (pid & 7) * (nwg >> 3) + (pid >> 3);  // bijective: nwg%8==0 always here
    const int nt = swz / nM;
    const int mt = swz - nt * nM;
    const int m0 = mt << 8;
    const int np0 = nt << 8;

    // staging source pointers, inverse-swizzled so linear LDS dest holds swizzled layout
    const unsigned short* aP[2];
    const unsigned short* bP[2];
    int ldst[2];
    #pragma unroll
    for (int l = 0; l < 2; l++) {
        int idx = l * 512 + t;
        int p = idx >> 3, pc = idx & 7;
        int spc = pc ^ (p & 7);
        int lr = 2 * p + (spc >> 2);
        int ke = (spc & 3) * 8;
        aP[l] = A + (size_t)(m0 + lr) * K + ke;
        bP[l] = Wi + (size_t)(np0 + lr) * K + ke;
        ldst[l] = idx * 16;
    }
    // fragment read base offsets (conflict-free)
    const int chR = (((fr & 1) << 2) | fg) ^ ((fr >> 1) & 7);
    const int aRd = (wr * 64 + (fr >> 1)) * 128 + chR * 16;
    const int bRd = (wc * 32 + (fr >> 1)) * 128 + chR * 16;

    f32x4 acc[8][4];
    f32x4 zero4 = {0.f, 0.f, 0.f, 0.f};
    #pragma unroll
    for (int i = 0; i < 8; i++)
        #pragma unroll
        for (int j = 0; j < 4; j++) acc[i][j] = zero4;
    s16x8 af[4], bf[4];

    // prologue: stage full T0 (A0,B0 first, then A1,B1), wait only for kh0
    async_cp16(aP[0], lds + ldst[0]);
    async_cp16(aP[1], lds + ldst[1]);
    async_cp16(bP[0], lds + 65536 + ldst[0]);
    async_cp16(bP[1], lds + 65536 + ldst[1]);
    async_cp16(aP[0] + 32, lds + 16384 + ldst[0]);
    async_cp16(aP[1] + 32, lds + 16384 + ldst[1]);
    async_cp16(bP[0] + 32, lds + 65536 + 16384 + ldst[0]);
    async_cp16(bP[1] + 32, lds + 65536 + 16384 + ldst[1]);
    G8_VM4(); G8_BAR(); G8_SCB();

    const int NT = K >> 6;
    for (int kt = 0; kt < NT - 1; kt++) {
        const int sA = (kt & 1) << 15;
        const int sB = 65536 + sA;
        const int nAb = sA ^ 32768;
        const int nBb = 65536 + nAb;
        const int kn = (kt + 1) << 6;
        // P1 (iq0,kh0): stage next A kh0
        G8_LDA(sA, 0); G8_LDB(sB);
        async_cp16(aP[0] + kn, lds + nAb + ldst[0]);
        async_cp16(aP[1] + kn, lds + nAb + ldst[1]);
        G8_MMA(0);
        // P2 (iq1,kh0): stage next B kh0; MMA overlaps the drain; then sync
        G8_LDA(sA, 1);
        async_cp16(bP[0] + kn, lds + nBb + ldst[0]);
        async_cp16(bP[1] + kn, lds + nBb + ldst[1]);
        G8_MMA(1);
        G8_VM4(); G8_BAR(); G8_SCB();   // prev A1B1 drained -> kh1 reads safe
        // P3 (iq0,kh1): stage next A kh1
        G8_LDA(sA + 16384, 0); G8_LDB(sB + 16384);
        async_cp16(aP[0] + kn + 32, lds + nAb + 16384 + ldst[0]);
        async_cp16(aP[1] + kn + 32, lds + nAb + 16384 + ldst[1]);
        G8_MMA(0);
        // P4 (iq1,kh1): stage next B kh1; MMA overlaps drain; then sync
        G8_LDA(sA + 16384, 1);
        async_cp16(bP[0] + kn + 32, lds + nBb + 16384 + ldst[0]);
        async_cp16(bP[1] + kn + 32, lds + nBb + 16384 + ldst[1]);
        G8_MMA(1);
        G8_VM4(); G8_BAR(); G8_SCB();   // next A0B0 drained -> next-tile kh0 reads safe
    }
    {   // final tile: no staging; only leftover in flight is this tile's A1B1
        const int sA = ((NT - 1) & 1) << 15;
        const int sB = 65536 + sA;
        G8_LDA(sA, 0); G8_LDB(sB);
        G8_MMA(0);
        G8_LDA(sA, 1);
        G8_MMA(1);
        G8_VM0(); G8_BAR(); G8_SCB();
        G8_LDA(sA + 16384, 0); G8_LDB(sB + 16384);
        G8_MMA(0);
        G8_LDA(sA + 16384, 1);
        G8_MMA(1);
    }

    // epilogue: pair acc[i][2jp] (lin) with acc[i][2jp+1] (gate)
    const int mB = m0 + wr * 128 + fg * 4;
    const int nB = (nt << 7) + wc * 32 + fr;  // true n
    if constexpr (EPI == 1) {
        // transposed V store: vT[(b*2048 + n)*2048 + tseq]
        const int b_ = m0 >> 11;
        unsigned short* vt = (unsigned short*)outp;
        #pragma unroll
        for (int i = 0; i < 8; i++)
            #pragma unroll
            for (int jp = 0; jp < 2; jp++) {
                const int n = nB + jp * 16;
                const float bn = bias[n], bgn = biasg[n];
                float g4[4];
                #pragma unroll
                for (int r = 0; r < 4; r++) {
                    float lin = acc[i][2 * jp][r] + bn;
                    float gt = acc[i][2 * jp + 1][r] + bgn;
                    g4[r] = lin / (1.f + __expf(-gt));
                }
                unsigned short* dst = vt + ((size_t)b_ * 2048 + n) * 2048 +
                                      (m0 & 2047) + wr * 128 + i * 16 + fg * 4;
                store4bf(dst, g4[0], g4[1], g4[2], g4[3]);
            }
    } else {
        #pragma unroll
        for (int i = 0; i < 8; i++)
            #pragma unroll
            for (int jp = 0; jp < 2; jp++) {
                const int n = nB + jp * 16;
                const float bn = bias[n], bgn = biasg[n];
                #pragma unroll
                for (int r = 0; r < 4; r++) {
                    const int m = mB + i * 16 + r;
                    float lin = acc[i][2 * jp][r] + bn;
                    float gt = acc[i][2 * jp + 1][r] + bgn;
                    float gv = lin / (1.f + __expf(-gt));
                    if constexpr (EPI == 0) {
                        ((unsigned short*)outp)[(size_t)m * Ntrue + n] = f2bf(gv);
                    } else if constexpr (EPI == 2) {
                        ((float*)outp)[(size_t)m * Ntrue + n] =
                            resid[(size_t)m * Ntrue + n] + gv;
                    } else {
                        float ge = 0.5f * gv * (1.f + erff(gv * 0.70710678118f));
                        ((unsigned short*)outp)[(size_t)m * Ntrue + n] = f2bf(ge);
                    }
                }
            }
    }
}

// ---------------- flash attention v2 (unchanged this round) ----------------
__global__ __launch_bounds__(256, 4) void attn_flash2(const unsigned short* __restrict__ Q,
                                                      const unsigned short* __restrict__ Kb,
                                                      const unsigned short* __restrict__ VT,
                                                      unsigned short* __restrict__ Y) {
    __shared__ unsigned short sK[64 * 128];
    __shared__ unsigned short sV[128 * 64];
    __shared__ unsigned short sP[4 * 1024];
    const int t = threadIdx.x, lane = t & 63, wv = t >> 6;
    const int bx = blockIdx.x;
    const int qblk = bx & 31;
    const int h = (bx >> 5) & 15;
    const int b = bx >> 9;
    const int q0 = qblk * 64 + wv * 16;
    const int fr = lane & 15, fg = lane >> 4;

    s16x8 qf[4];
    const unsigned short* qbase = Q + ((size_t)(b * TT + q0 + fr)) * DD + h * HDD + fg * 8;
    #pragma unroll
    for (int s = 0; s < 4; s++) qf[s] = *(const s16x8*)(qbase + s * 32);

    const unsigned short* kSrc[4];
    const unsigned short* vSrc[4];
    #pragma unroll
    for (int r = 0; r < 4; r++) {
        int R = r * 16 + (t >> 4);
        int c = (t & 15) ^ ((t >> 4) & 15);
        kSrc[r] = Kb + (size_t)(b * TT + R) * DD + h * HDD + c * 8;
        int hd = r * 32 + (t >> 3);
        int cv = (t & 7) ^ ((t >> 3) & 7);
        vSrc[r] = VT + ((size_t)((b * HH + h) * HDD + hd)) * TT + cv * 8;
    }
    unsigned short* sPw = sP + wv * 1024;

    f32x4 zero4 = {0.f, 0.f, 0.f, 0.f};
    f32x4 o[8];
    #pragma unroll
    for (int jo = 0; jo < 8; jo++) o[jo] = zero4;
    float Mx[4], L[4];
    #pragma unroll
    for (int r = 0; r < 4; r++) { Mx[r] = -1e30f; L[r] = 0.f; }
    const float scale = 0.08838834764831845f;

    for (int tk0 = 0; tk0 < TT; tk0 += 64) {
        #pragma unroll
        for (int r = 0; r < 4; r++) {
            async_cp16(kSrc[r] + (size_t)tk0 * DD, sK + r * 2048 + t * 8);
            async_cp16(vSrc[r] + tk0, sV + r * 2048 + t * 8);
        }
        __syncthreads();

        f32x4 sac[4];
        #pragma unroll
        for (int j = 0; j < 4; j++) sac[j] = zero4;
        #pragma unroll
        for (int j = 0; j < 4; j++)
            #pragma unroll
            for (int s = 0; s < 4; s++) {
                s16x8 kf = *(const s16x8*)(sK + (j * 16 + fr) * 128 + (((s * 4 + fg) ^ fr) * 8));
                sac[j] = __builtin_amdgcn_mfma_f32_16x16x32_bf16(qf[s], kf, sac[j], 0, 0, 0);
            }

        float alpha[4];
        #pragma unroll
        for (int j = 0; j < 4; j++)
            #pragma unroll
            for (int r = 0; r < 4; r++) sac[j][r] *= scale;
        #pragma unroll
        for (int r = 0; r < 4; r++) {
            float mx = fmaxf(fmaxf(sac[0][r], sac[1][r]), fmaxf(sac[2][r], sac[3][r]));
            mx = fmaxf(mx, __shfl_xor(mx, 1));
            mx = fmaxf(mx, __shfl_xor(mx, 2));
            mx = fmaxf(mx, __shfl_xor(mx, 4));
            mx = fmaxf(mx, __shfl_xor(mx, 8));
            float mnew = fmaxf(Mx[r], mx);
            alpha[r] = __expf(Mx[r] - mnew);
            Mx[r] = mnew;
        }
        float rs[4] = {0.f, 0.f, 0.f, 0.f};
        #pragma unroll
        for (int j = 0; j < 4; j++)
            #pragma unroll
            for (int r = 0; r < 4; r++) {
                float p = __expf(sac[j][r] - Mx[r]);
                rs[r] += p;
                int qr = fg * 4 + r;
                int cc = (j * 2 + (fr >> 3)) ^ (qr & 7);
                sPw[qr * 64 + cc * 8 + (fr & 7)] = f2bf(p);
            }
        #pragma unroll
        for (int r = 0; r < 4; r++) {
            float tsum = rs[r];
            tsum += __shfl_xor(tsum, 1);
            tsum += __shfl_xor(tsum, 2);
            tsum += __shfl_xor(tsum, 4);
            tsum += __shfl_xor(tsum, 8);
            L[r] = L[r] * alpha[r] + tsum;
        }
        #pragma unroll
        for (int jo = 0; jo < 8; jo++)
            #pragma unroll
            for (int r = 0; r < 4; r++) o[jo][r] *= alpha[r];

        s16x8 pa[2];
        #pragma unroll
        for (int ks = 0; ks < 2; ks++)
            pa[ks] = *(const s16x8*)(sPw + fr * 64 + (((ks * 4 + fg) ^ (fr & 7)) * 8));
        #pragma unroll
        for (int jo = 0; jo < 8; jo++)
            #pragma unroll
            for (int ks = 0; ks < 2; ks++) {
                s16x8 vf = *(const s16x8*)(sV + (jo * 16 + fr) * 64 + (((ks * 4 + fg) ^ (fr & 7)) * 8));
                o[jo] = __builtin_amdgcn_mfma_f32_16x16x32_bf16(pa[ks], vf, o[jo], 0, 0, 0);
            }
        __syncthreads();
    }
    float Linv[4];
    #pragma unroll
    for (int r = 0; r < 4; r++) Linv[r] = 1.f / L[r];
    #pragma unroll
    for (int jo = 0; jo < 8; jo++)
        #pragma unroll
        for (int r = 0; r < 4; r++) {
            float val = o[jo][r] * Linv[r];
            Y[((size_t)(b * TT + q0 + fg * 4 + r)) * DD + h * HDD + jo * 16 + fr] = f2bf(val);
        }
}

// ---------------- launch ----------------
extern "C" void kernel_launch(void* const* d_in, const int* in_sizes, int n_in,
                              void* d_out, int out_size, void* d_ws, size_t ws_size,
                              hipStream_t stream) {
    const float* x = (const float*)d_in[0];
    auto F = [&](int i) { return (const float*)d_in[i]; };
    char* ws = (char*)d_ws;
    const size_t MB = 1ull << 20;

    unsigned short* wi_q  = (unsigned short*)(ws + 0 * MB);
    unsigned short* wi_k  = (unsigned short*)(ws + 16 * MB);
    unsigned short* wi_v  = (unsigned short*)(ws + 32 * MB);
    unsigned short* wi_o  = (unsigned short*)(ws + 48 * MB);
    unsigned short* wi_in = (unsigned short*)(ws + 64 * MB);
    unsigned short* wi_ot = (unsigned short*)(ws + 128 * MB);
    cvt_ilv<<<dim3(8192), dim3(256), 0, stream>>>(F(1), F(3), wi_q, 9);
    cvt_ilv<<<dim3(8192), dim3(256), 0, stream>>>(F(5), F(7), wi_k, 9);
    cvt_ilv<<<dim3(8192), dim3(256), 0, stream>>>(F(9), F(11), wi_v, 9);
    cvt_ilv<<<dim3(8192), dim3(256), 0, stream>>>(F(13), F(15), wi_o, 9);
    cvt_ilv<<<dim3(32768), dim3(256), 0, stream>>>(F(17), F(19), wi_in, 9);
    cvt_ilv<<<dim3(32768), dim3(256), 0, stream>>>(F(21), F(23), wi_ot, 11);

    unsigned short* hbf = (unsigned short*)(ws + 192 * MB);
    unsigned short* qb  = (unsigned short*)(ws + 208 * MB);
    unsigned short* kb  = (unsigned short*)(ws + 224 * MB);
    unsigned short* vtb = (unsigned short*)(ws + 240 * MB);
    unsigned short* yb  = (unsigned short*)(ws + 256 * MB);
    unsigned short* ub  = (unsigned short*)(ws + 208 * MB);  // overlaps q/k/vT/y (dead by then)
    float* x1 = (float*)(ws + 272 * MB);

    ln_bf16<<<dim3(MROWS), dim3(256), 0, stream>>>(x, F(25), F(26), hbf);

    dim3 blk(512);
    gemm_gated8<0><<<dim3(256), blk, 0, stream>>>(hbf, wi_q, F(2), F(4), nullptr, qb, MROWS, DD, DD);
    gemm_gated8<0><<<dim3(256), blk, 0, stream>>>(hbf, wi_k, F(6), F(8), nullptr, kb, MROWS, DD, DD);
    gemm_gated8<1><<<dim3(256), blk, 0, stream>>>(hbf, wi_v, F(10), F(12), nullptr, vtb, MROWS, DD, DD);

    attn_flash2<<<dim3(1024), dim3(256), 0, stream>>>(qb, kb, vtb, yb);

    gemm_gated8<2><<<dim3(256), blk, 0, stream>>>(yb, wi_o, F(14), F(16), x, x1, MROWS, DD, DD);

    ln_bf16<<<dim3(MROWS), dim3(256), 0, stream>>>(x1, F(27), F(28), hbf);

    gemm_gated8<3><<<dim3(1024), blk, 0, stream>>>(hbf, wi_in, F(18), F(20), nullptr, ub, MROWS, 4 * DD, DD);
    gemm_gated8<2><<<dim3(256), blk, 0, stream>>>(ub, wi_ot, F(22), F(24), x1, (float*)d_out, MROWS, DD, 4 * DD);
}